// Round 1
// baseline (137.912 us; speedup 1.0000x reference)
//
#include <hip/hip_runtime.h>

#define VDIM 20
#define NPAIR 190
#define EMB 64
#define ATT 32
#define SPB 4          // samples (waves) per block
#define EPAD 65        // e row pad: bank = (i*65+d)%32 = (i+d)%32 -> conflict-free
#define WPAD 36        // w1t row pad: 144B stride keeps float4 16B-aligned

__global__ void afm_fwd(const int* __restrict__ feats,
                        const float* __restrict__ fvals,
                        const float* __restrict__ emb,
                        const float* __restrict__ btab,
                        const float* __restrict__ gbias,
                        const float* __restrict__ w1,
                        const float* __restrict__ b1,
                        const float* __restrict__ w2,
                        const float* __restrict__ pw,
                        float* __restrict__ out,
                        int B)
{
    __shared__ __align__(16) float ls_w1[EMB * WPAD];   // transposed: [d][a]
    __shared__ float ls_pw[EMB];
    __shared__ float ls_b1[ATT];
    __shared__ float ls_w2[ATT];
    __shared__ float ls_e[SPB][VDIM * EPAD];
    __shared__ int   ls_f[SPB][VDIM];
    __shared__ float ls_v[SPB][VDIM];

    const int tid  = threadIdx.x;
    const int wv   = tid >> 6;
    const int lane = tid & 63;
    const int b    = blockIdx.x * SPB + wv;

    // ---- cooperative staging of shared weights (coalesced global reads) ----
    for (int k = tid; k < ATT * EMB; k += SPB * 64) {
        int a = k >> 6, d = k & 63;
        ls_w1[d * WPAD + a] = w1[k];          // transpose on store
    }
    if (tid < EMB)                        ls_pw[tid]       = pw[tid];
    if (tid >= 128 && tid < 128 + ATT)    ls_b1[tid - 128] = b1[tid - 128];
    if (tid >= 192 && tid < 192 + ATT)    ls_w2[tid - 192] = w2[tid - 192];

    // ---- per-sample feature/value load + first-order bias term ----
    float fb = 0.f;
    if (b < B && lane < VDIM) {
        int   f = feats[b * VDIM + lane];
        float v = fvals[b * VDIM + lane];
        ls_f[wv][lane] = f;
        ls_v[wv][lane] = v;
        fb = btab[f] * v;
    }
    __syncthreads();

    if (b < B) {
        // gather embeddings: lane d loads column d of each of the 20 rows (coalesced 256B/row)
        #pragma unroll
        for (int f = 0; f < VDIM; ++f) {
            int   ff = ls_f[wv][f];
            float v  = ls_v[wv][f];
            ls_e[wv][f * EPAD + lane] = emb[(size_t)ff * EMB + lane] * v;
        }
    }
    __syncthreads();   // last barrier in the kernel; early-return below is safe

    if (b >= B) return;

    // ---- per-lane pair assignment: pairs p, p+64, p+128 (190 -> 192 padded) ----
    int  bi[3], bj[3];
    bool val[3];
    #pragma unroll
    for (int k = 0; k < 3; ++k) {
        int p  = lane + 64 * k;
        val[k] = (p < NPAIR);
        int pp = val[k] ? p : 0;
        int i = 0, rem = pp;
        while (rem >= (VDIM - 1 - i)) { rem -= (VDIM - 1 - i); ++i; }
        bi[k] = i * EPAD;
        bj[k] = (i + 1 + rem) * EPAD;
    }

    const float* ew = ls_e[wv];
    float h0[ATT], h1[ATT], h2[ATT];
    #pragma unroll
    for (int a = 0; a < ATT; ++a) { h0[a] = 0.f; h1[a] = 0.f; h2[a] = 0.f; }
    float s0 = 0.f, s1 = 0.f, s2 = 0.f;

    // ---- main loop: 96 FMA + 3 FMA per d, 15 LDS ops (w1 reads are broadcast) ----
    #pragma unroll 2
    for (int d = 0; d < EMB; ++d) {
        float e0 = ew[bi[0] + d] * ew[bj[0] + d];
        float e1 = ew[bi[1] + d] * ew[bj[1] + d];
        float e2 = ew[bi[2] + d] * ew[bj[2] + d];
        float pd = ls_pw[d];
        s0 = fmaf(e0, pd, s0);
        s1 = fmaf(e1, pd, s1);
        s2 = fmaf(e2, pd, s2);
        const float4* wc = reinterpret_cast<const float4*>(&ls_w1[d * WPAD]);
        #pragma unroll
        for (int q = 0; q < 8; ++q) {
            float4 w = wc[q];
            h0[4*q+0] = fmaf(w.x, e0, h0[4*q+0]);
            h0[4*q+1] = fmaf(w.y, e0, h0[4*q+1]);
            h0[4*q+2] = fmaf(w.z, e0, h0[4*q+2]);
            h0[4*q+3] = fmaf(w.w, e0, h0[4*q+3]);
            h1[4*q+0] = fmaf(w.x, e1, h1[4*q+0]);
            h1[4*q+1] = fmaf(w.y, e1, h1[4*q+1]);
            h1[4*q+2] = fmaf(w.z, e1, h1[4*q+2]);
            h1[4*q+3] = fmaf(w.w, e1, h1[4*q+3]);
            h2[4*q+0] = fmaf(w.x, e2, h2[4*q+0]);
            h2[4*q+1] = fmaf(w.y, e2, h2[4*q+1]);
            h2[4*q+2] = fmaf(w.z, e2, h2[4*q+2]);
            h2[4*q+3] = fmaf(w.w, e2, h2[4*q+3]);
        }
    }

    // ---- attention MLP epilogue: logits = w2 . relu(h + b1) ----
    float lg0 = 0.f, lg1 = 0.f, lg2 = 0.f;
    #pragma unroll
    for (int a = 0; a < ATT; ++a) {
        float bb = ls_b1[a], wa = ls_w2[a];
        lg0 = fmaf(fmaxf(h0[a] + bb, 0.f), wa, lg0);
        lg1 = fmaf(fmaxf(h1[a] + bb, 0.f), wa, lg1);
        lg2 = fmaf(fmaxf(h2[a] + bb, 0.f), wa, lg2);
    }

    const float NEG = -3.4e38f;
    float lmax = fmaxf(val[0] ? lg0 : NEG, fmaxf(val[1] ? lg1 : NEG, val[2] ? lg2 : NEG));
    #pragma unroll
    for (int off = 32; off; off >>= 1)
        lmax = fmaxf(lmax, __shfl_xor(lmax, off));

    float wk0 = val[0] ? expf(lg0 - lmax) : 0.f;
    float wk1 = val[1] ? expf(lg1 - lmax) : 0.f;
    float wk2 = val[2] ? expf(lg2 - lmax) : 0.f;

    float num = fmaf(wk0, s0, fmaf(wk1, s1, wk2 * s2));
    float den = wk0 + wk1 + wk2;
    #pragma unroll
    for (int off = 32; off; off >>= 1) {
        num += __shfl_xor(num, off);
        den += __shfl_xor(den, off);
        fb  += __shfl_xor(fb,  off);
    }

    if (lane == 0)
        out[b] = num / den + fb + gbias[0];
}

extern "C" void kernel_launch(void* const* d_in, const int* in_sizes, int n_in,
                              void* d_out, int out_size, void* d_ws, size_t ws_size,
                              hipStream_t stream)
{
    const int*   feats = (const int*)  d_in[0];
    const float* fvals = (const float*)d_in[1];
    const float* emb   = (const float*)d_in[2];
    const float* btab  = (const float*)d_in[3];
    const float* gb    = (const float*)d_in[4];
    const float* w1    = (const float*)d_in[5];
    const float* b1    = (const float*)d_in[6];
    const float* w2    = (const float*)d_in[7];
    const float* pw    = (const float*)d_in[8];
    float*       out   = (float*)d_out;

    const int B    = in_sizes[0] / VDIM;
    const int grid = (B + SPB - 1) / SPB;
    afm_fwd<<<grid, SPB * 64, 0, stream>>>(feats, fvals, emb, btab, gb,
                                           w1, b1, w2, pw, out, B);
}

// Round 2
// 74.427 us; speedup vs baseline: 1.8530x; 1.8530x over previous
//
#include <hip/hip_runtime.h>

#define VDIM 20
#define NPAIR 190
#define EMB 64
#define ATT 32
#define EPAD 25   // ls_e[d][i] stride 25: bank=(25d+i)%32, 2-way max on all access patterns

typedef __attribute__((ext_vector_type(8))) short bf16x8;   // 8 bf16 (4 VGPRs)
typedef __attribute__((ext_vector_type(4))) float f32x4;    // MFMA accumulator

__device__ __forceinline__ short f2bf(float f) {
    unsigned u = __builtin_bit_cast(unsigned, f);
    u += 0x7fffu + ((u >> 16) & 1u);          // round-to-nearest-even
    return (short)(u >> 16);
}

__global__ __launch_bounds__(256, 4)
void afm_fwd(const int* __restrict__ feats, const float* __restrict__ fvals,
             const float* __restrict__ emb, const float* __restrict__ btab,
             const float* __restrict__ gbias, const float* __restrict__ w1,
             const float* __restrict__ b1, const float* __restrict__ w2,
             const float* __restrict__ pw, float* __restrict__ out, int B)
{
    __shared__ float ls_e[EMB * EPAD];   // transposed: e^T[d][i] = emb[f_i][d]*v_i
    __shared__ float ls_s[192];          // s_p = sum_d ele_p[d]*pw[d]
    __shared__ float ls_fb[VDIM];
    __shared__ float ls_red[3][4];       // [0]=pmax [1]=pnum [2]=pden per wave
    __shared__ int   ls_f[VDIM];
    __shared__ float ls_v[VDIM];

    const int tid  = threadIdx.x;
    const int wv   = tid >> 6;           // wave 0..3, owns pairs [48w, 48w+48)
    const int lane = tid & 63;
    const int g    = lane >> 4;          // k-block / row-group index
    const int a0   = lane & 15;          // att-col / pair-row index
    const int b    = blockIdx.x;

    // ---- features, values, first-order bias ----
    if (tid < VDIM) {
        int   f = feats[b * VDIM + tid];
        float v = fvals[b * VDIM + tid];
        ls_f[tid]  = f;
        ls_v[tid]  = v;
        ls_fb[tid] = btab[f] * v;
    }
    __syncthreads();

    // ---- gather embeddings, scale, store transposed [d][i] ----
    #pragma unroll
    for (int k = 0; k < 5; ++k) {
        int idx = tid + 256 * k;         // idx = i*64 + d, covers 20*64
        int i = idx >> 6, d = idx & 63;
        ls_e[d * EPAD + i] = emb[(size_t)ls_f[i] * EMB + d] * ls_v[i];
    }

    // ---- B fragments: B[k][n] = w1[n][k], n = a0+16*nt, k = 32*ks + 8*g + e ----
    bf16x8 bv[2][2];
    #pragma unroll
    for (int nt = 0; nt < 2; ++nt)
        #pragma unroll
        for (int ks = 0; ks < 2; ++ks) {
            const float* wp = w1 + (a0 + 16 * nt) * EMB + ks * 32 + g * 8;
            #pragma unroll
            for (int e = 0; e < 8; ++e) bv[nt][ks][e] = f2bf(wp[e]);
        }
    // pred_w values at this lane's k positions
    float pwr[2][8];
    #pragma unroll
    for (int ks = 0; ks < 2; ++ks)
        #pragma unroll
        for (int e = 0; e < 8; ++e) pwr[ks][e] = pw[ks * 32 + g * 8 + e];

    // ---- pair (i,j) for this lane's 3 A-row slots (row = a0 of tile mt) ----
    int ia[3], ja[3];
    #pragma unroll
    for (int mt = 0; mt < 3; ++mt) {
        int p = wv * 48 + mt * 16 + a0;
        if (p >= NPAIR) p = 0;           // padded rows: harmless dummy pair
        int i = 0, rem = p;
        while (rem >= VDIM - 1 - i) { rem -= VDIM - 1 - i; ++i; }
        ia[mt] = i; ja[mt] = i + 1 + rem;
    }
    __syncthreads();

    // ---- main: build A from e_i*e_j (fp32), fold s-partials, MFMA in bf16 ----
    f32x4 acc[3][2];
    #pragma unroll
    for (int mt = 0; mt < 3; ++mt)
        #pragma unroll
        for (int nt = 0; nt < 2; ++nt)
            acc[mt][nt] = (f32x4){0.f, 0.f, 0.f, 0.f};
    float sp[3] = {0.f, 0.f, 0.f};

    #pragma unroll
    for (int ks = 0; ks < 2; ++ks) {
        bf16x8 av[3];
        #pragma unroll
        for (int mt = 0; mt < 3; ++mt) {
            const float* ei = ls_e + (ks * 32 + g * 8) * EPAD + ia[mt];
            const float* ej = ls_e + (ks * 32 + g * 8) * EPAD + ja[mt];
            #pragma unroll
            for (int e = 0; e < 8; ++e) {
                float f = ei[e * EPAD] * ej[e * EPAD];
                sp[mt] = fmaf(f, pwr[ks][e], sp[mt]);
                av[mt][e] = f2bf(f);
            }
        }
        #pragma unroll
        for (int mt = 0; mt < 3; ++mt)
            #pragma unroll
            for (int nt = 0; nt < 2; ++nt)
                acc[mt][nt] = __builtin_amdgcn_mfma_f32_16x16x32_bf16(
                                  av[mt], bv[nt][ks], acc[mt][nt], 0, 0, 0);
    }

    // ---- s_p: reduce k-block partials across groups, publish to LDS ----
    #pragma unroll
    for (int mt = 0; mt < 3; ++mt) {
        float s = sp[mt];
        s += __shfl_xor(s, 16);
        s += __shfl_xor(s, 32);
        if (g == 0) ls_s[wv * 48 + mt * 16 + a0] = s;
    }
    __syncthreads();

    // ---- logits: w2 . relu(h + b1); C layout col=lane&15, row=(lane>>4)*4+reg ----
    float b1v0 = b1[a0], b1v1 = b1[a0 + 16];
    float w2v0 = w2[a0], w2v1 = w2[a0 + 16];
    float lg[3][4];
    #pragma unroll
    for (int mt = 0; mt < 3; ++mt)
        #pragma unroll
        for (int r = 0; r < 4; ++r) {
            float c = fmaxf(acc[mt][0][r] + b1v0, 0.f) * w2v0
                    + fmaxf(acc[mt][1][r] + b1v1, 0.f) * w2v1;
            c += __shfl_xor(c, 1);
            c += __shfl_xor(c, 2);
            c += __shfl_xor(c, 4);
            c += __shfl_xor(c, 8);
            lg[mt][r] = c;               // logit of pair wv*48+mt*16+g*4+r, repl x16
        }

    // ---- softmax (cross-wave via LDS) + weighted sum of s_p ----
    float m = -3.4e38f;
    #pragma unroll
    for (int mt = 0; mt < 3; ++mt)
        #pragma unroll
        for (int r = 0; r < 4; ++r) {
            int p = wv * 48 + mt * 16 + g * 4 + r;
            if (p < NPAIR) m = fmaxf(m, lg[mt][r]);
        }
    #pragma unroll
    for (int off = 32; off; off >>= 1) m = fmaxf(m, __shfl_xor(m, off));
    if (lane == 0) ls_red[0][wv] = m;
    __syncthreads();

    float gm = fmaxf(fmaxf(ls_red[0][0], ls_red[0][1]),
                     fmaxf(ls_red[0][2], ls_red[0][3]));
    float num = 0.f, den = 0.f;
    #pragma unroll
    for (int mt = 0; mt < 3; ++mt)
        #pragma unroll
        for (int r = 0; r < 4; ++r) {
            int p = wv * 48 + mt * 16 + g * 4 + r;
            if (p < NPAIR) {
                float wgt = __expf(lg[mt][r] - gm);
                num = fmaf(wgt, ls_s[p], num);   // x16 replication cancels in N/D
                den += wgt;
            }
        }
    #pragma unroll
    for (int off = 32; off; off >>= 1) {
        num += __shfl_xor(num, off);
        den += __shfl_xor(den, off);
    }
    if (lane == 0) { ls_red[1][wv] = num; ls_red[2][wv] = den; }
    __syncthreads();

    if (tid == 0) {
        float N = ls_red[1][0] + ls_red[1][1] + ls_red[1][2] + ls_red[1][3];
        float D = ls_red[2][0] + ls_red[2][1] + ls_red[2][2] + ls_red[2][3];
        float fbt = 0.f;
        #pragma unroll
        for (int t = 0; t < VDIM; ++t) fbt += ls_fb[t];
        out[b] = N / D + fbt + gbias[0];
    }
}

extern "C" void kernel_launch(void* const* d_in, const int* in_sizes, int n_in,
                              void* d_out, int out_size, void* d_ws, size_t ws_size,
                              hipStream_t stream)
{
    const int*   feats = (const int*)  d_in[0];
    const float* fvals = (const float*)d_in[1];
    const float* emb   = (const float*)d_in[2];
    const float* btab  = (const float*)d_in[3];
    const float* gb    = (const float*)d_in[4];
    const float* w1    = (const float*)d_in[5];
    const float* b1    = (const float*)d_in[6];
    const float* w2    = (const float*)d_in[7];
    const float* pw    = (const float*)d_in[8];
    float*       out   = (float*)d_out;

    const int B = in_sizes[0] / VDIM;
    afm_fwd<<<B, 256, 0, stream>>>(feats, fvals, emb, btab, gb,
                                   w1, b1, w2, pw, out, B);
}